// Round 6
// baseline (730.955 us; speedup 1.0000x reference)
//
#include <hip/hip_runtime.h>
#include <hip/hip_bf16.h>
#include <cstdint>
#include <cstddef>

static constexpr int Sq  = 2048;
static constexpr int Dm  = 2048;
static constexpr int NH  = 32;
static constexpr int HDm = 64;
static constexpr int FFm = 8192;

typedef __bf16 bf16x8 __attribute__((ext_vector_type(8)));
typedef float  f32x4  __attribute__((ext_vector_type(4)));
typedef unsigned short ushort4v __attribute__((ext_vector_type(4)));

__device__ __forceinline__ void async_ld16(const void* g, void* l) {
  __builtin_amdgcn_global_load_lds((const __attribute__((address_space(1))) void*)g,
                                   (__attribute__((address_space(3))) void*)l, 16, 0, 0);
}

#define MFMA16(a, b, c) __builtin_amdgcn_mfma_f32_16x16x32_bf16(a, b, c, 0, 0, 0)

// ---------- transpose + cast: in[K][N] f32 -> out[N][K] bf16, vectorized ----
__global__ __launch_bounds__(256)
void tcast_kernel(const float* __restrict__ in, __hip_bfloat16* __restrict__ out,
                  int K, int N) {
  __shared__ float tile[64][65];
  const int tc = blockIdx.x * 64;
  const int tr = blockIdx.y * 64;
  const int t = threadIdx.x;
  const int f16 = t & 15;
  const int rg  = t >> 4;
#pragma unroll
  for (int k = 0; k < 4; ++k) {
    const int r = rg + 16 * k;
    const float4 v = *(const float4*)(in + (size_t)(tr + r) * N + tc + f16 * 4);
    tile[r][f16 * 4 + 0] = v.x;
    tile[r][f16 * 4 + 1] = v.y;
    tile[r][f16 * 4 + 2] = v.z;
    tile[r][f16 * 4 + 3] = v.w;
  }
  __syncthreads();
#pragma unroll
  for (int k = 0; k < 4; ++k) {
    const int cc = rg + 16 * k;
    ushort4v o;
#pragma unroll
    for (int j = 0; j < 4; ++j) {
      union { __hip_bfloat16 h; unsigned short u; } cv;
      cv.h = __float2bfloat16(tile[f16 * 4 + j][cc]);
      o[j] = cv.u;
    }
    *(ushort4v*)(out + (size_t)(tc + cc) * K + tr + f16 * 4) = o;
  }
}

// ---------- layernorm row kernel: x f32 -> out bf16 ----------
__global__ __launch_bounds__(256)
void ln_kernel(const float* __restrict__ x, const float* __restrict__ g,
               const float* __restrict__ b, __hip_bfloat16* __restrict__ out) {
  __shared__ float red[4];
  const int t = threadIdx.x;
  const float* xr = x + (size_t)blockIdx.x * Dm;
  float v[8];
  float s = 0.f;
#pragma unroll
  for (int i = 0; i < 8; ++i) { v[i] = xr[t + i * 256]; s += v[i]; }
#pragma unroll
  for (int off = 32; off > 0; off >>= 1) s += __shfl_down(s, off, 64);
  if ((t & 63) == 0) red[t >> 6] = s;
  __syncthreads();
  const float mean = (red[0] + red[1] + red[2] + red[3]) * (1.f / Dm);
  __syncthreads();
  float vs = 0.f;
#pragma unroll
  for (int i = 0; i < 8; ++i) { float d = v[i] - mean; vs += d * d; }
#pragma unroll
  for (int off = 32; off > 0; off >>= 1) vs += __shfl_down(vs, off, 64);
  if ((t & 63) == 0) red[t >> 6] = vs;
  __syncthreads();
  const float inv = rsqrtf((red[0] + red[1] + red[2] + red[3]) * (1.f / Dm) + 1e-5f);
  __hip_bfloat16* orow = out + (size_t)blockIdx.x * Dm;
#pragma unroll
  for (int i = 0; i < 8; ++i) {
    int c = t + i * 256;
    orow[c] = __float2bfloat16((v[i] - mean) * inv * g[c] + b[c]);
  }
}

// ---------- fused: resb += 3 partial slots; layernorm(resb) -> out bf16 ------
__global__ __launch_bounds__(256)
void lnfuse_kernel(float* __restrict__ resb, const __hip_bfloat16* __restrict__ part,
                   const float* __restrict__ g, const float* __restrict__ b,
                   __hip_bfloat16* __restrict__ out) {
  __shared__ float red[4];
  const int t = threadIdx.x;
  const size_t st = (size_t)Sq * Dm;
  float* xr = resb + (size_t)blockIdx.x * Dm;
  const __hip_bfloat16* p0 = part + (size_t)blockIdx.x * Dm;
  float v[8];
  float s = 0.f;
#pragma unroll
  for (int i = 0; i < 8; ++i) {
    int c = t + i * 256;
    v[i] = xr[c] + (float)p0[c] + (float)p0[st + c] + (float)p0[2 * st + c];
    xr[c] = v[i];
    s += v[i];
  }
#pragma unroll
  for (int off = 32; off > 0; off >>= 1) s += __shfl_down(s, off, 64);
  if ((t & 63) == 0) red[t >> 6] = s;
  __syncthreads();
  const float mean = (red[0] + red[1] + red[2] + red[3]) * (1.f / Dm);
  __syncthreads();
  float vs = 0.f;
#pragma unroll
  for (int i = 0; i < 8; ++i) { float d = v[i] - mean; vs += d * d; }
#pragma unroll
  for (int off = 32; off > 0; off >>= 1) vs += __shfl_down(vs, off, 64);
  if ((t & 63) == 0) red[t >> 6] = vs;
  __syncthreads();
  const float inv = rsqrtf((red[0] + red[1] + red[2] + red[3]) * (1.f / Dm) + 1e-5f);
  __hip_bfloat16* orow = out + (size_t)blockIdx.x * Dm;
#pragma unroll
  for (int i = 0; i < 8; ++i) {
    int c = t + i * 256;
    orow[c] = __float2bfloat16((v[i] - mean) * inv * g[c] + b[c]);
  }
}

// ---------- out[i] += sum of 3 bf16 partial slots, vectorized x4 ----------
__global__ __launch_bounds__(256)
void addp3_kernel(float* __restrict__ out, const __hip_bfloat16* __restrict__ p) {
  const size_t i = ((size_t)blockIdx.x * 256 + threadIdx.x) * 4;
  const size_t st = (size_t)Sq * Dm;
  float4 o = *(const float4*)(out + i);
#pragma unroll
  for (int s = 0; s < 3; ++s) {
    const __hip_bfloat16* pp = p + s * st + i;
    o.x += (float)pp[0]; o.y += (float)pp[1]; o.z += (float)pp[2]; o.w += (float)pp[3];
  }
  *(float4*)(out + i) = o;
}

// ---------- 256x256 4-phase bf16 MFMA GEMM (best-measured config) ----------
template <int EPI>
__global__ __launch_bounds__(512)
void gemm256_kernel(const __hip_bfloat16* __restrict__ A,
                    const __hip_bfloat16* __restrict__ Bt,
                    int N, int K,
                    const float* __restrict__ bias,
                    __hip_bfloat16* __restrict__ outb,
                    __hip_bfloat16* __restrict__ qo,
                    __hip_bfloat16* __restrict__ ko,
                    __hip_bfloat16* __restrict__ vo) {
  __shared__ __align__(16) __hip_bfloat16 As[2][256 * 64];
  __shared__ __align__(16) __hip_bfloat16 Bs[2][256 * 64];
  const int t = threadIdx.x;
  const int lane = t & 63, w = t >> 6, quad = lane >> 4, l16 = lane & 15;
  const int wmi = w >> 2, wni = w & 3;
  const int nwg = gridDim.x;
  const int id = blockIdx.x;
  const int xcd = id & 7, q = nwg >> 3, r_ = nwg & 7;
  const int swz = (xcd < r_ ? xcd * (q + 1) : r_ * (q + 1) + (xcd - r_) * q) + (id >> 3);
  const int bm = swz & 7, bn = swz >> 3;
  const __hip_bfloat16* Abase = A + (size_t)bm * 256 * K;
  const __hip_bfloat16* Bbase = Bt + (size_t)bn * 256 * K;
  const int kT = K / 64;

  const int c0 = t, c1 = t + 512;
  const int r0 = c0 >> 3, k0c = (c0 & 7) ^ (r0 & 7);
  const int r1 = c1 >> 3, k1c = (c1 & 7) ^ (r1 & 7);
  const size_t o0 = (size_t)r0 * K + k0c * 8;
  const size_t o1 = (size_t)r1 * K + k1c * 8;
  const size_t halfO = (size_t)128 * K;

  auto stA = [&](int b, int h, int k0) {
    async_ld16(Abase + h * halfO + o0 + k0, &As[b][h * 8192 + c0 * 8]);
    async_ld16(Abase + h * halfO + o1 + k0, &As[b][h * 8192 + c1 * 8]);
  };
  auto stB = [&](int b, int h, int k0) {
    async_ld16(Bbase + h * halfO + o0 + k0, &Bs[b][h * 8192 + c0 * 8]);
    async_ld16(Bbase + h * halfO + o1 + k0, &Bs[b][h * 8192 + c1 * 8]);
  };
  auto ldsA = [&](int b, int r, int ks) {
    return *(const bf16x8*)(&As[b][r * 64 + (((ks * 4 + quad) ^ (r & 7)) << 3)]);
  };
  auto ldsB = [&](int b, int r, int ks) {
    return *(const bf16x8*)(&Bs[b][r * 64 + (((ks * 4 + quad) ^ (r & 7)) << 3)]);
  };

  f32x4 acc[8][4] = {};
  bf16x8 af0[4][2], af1[4][2], bf0[2][2], bf1[2][2];
  const int arow = wmi * 128 + l16;
  const int brow = wni * 64 + l16;

#define BAR() asm volatile("s_barrier" ::: "memory")
#define LGKM0() do { asm volatile("s_waitcnt lgkmcnt(0)" ::: "memory"); \
                     __builtin_amdgcn_sched_barrier(0); } while (0)

  stA(0, 0, 0); stA(0, 1, 0); stB(0, 0, 0); stB(0, 1, 0);
  stA(1, 0, 64); stB(1, 0, 64);
  asm volatile("s_waitcnt vmcnt(4)" ::: "memory");
  BAR();

  for (int tt = 0; tt < kT; ++tt) {
    const int buf = tt & 1;
    const int kn1 = (tt + 1) * 64, kn2 = (tt + 2) * 64;
    // ---- phase 0 ----
#pragma unroll
    for (int mt = 0; mt < 4; ++mt) {
      af0[mt][0] = ldsA(buf, arow + mt * 16, 0);
      af0[mt][1] = ldsA(buf, arow + mt * 16, 1);
    }
#pragma unroll
    for (int nt = 0; nt < 2; ++nt) {
      bf0[nt][0] = ldsB(buf, brow + nt * 16, 0);
      bf0[nt][1] = ldsB(buf, brow + nt * 16, 1);
    }
    if (tt + 1 < kT) stA(buf ^ 1, 1, kn1);
    BAR(); LGKM0();
    __builtin_amdgcn_s_setprio(1);
#pragma unroll
    for (int mt = 0; mt < 4; ++mt)
#pragma unroll
      for (int nt = 0; nt < 2; ++nt) {
        acc[mt][nt] = MFMA16(af0[mt][0], bf0[nt][0], acc[mt][nt]);
        acc[mt][nt] = MFMA16(af0[mt][1], bf0[nt][1], acc[mt][nt]);
      }
    __builtin_amdgcn_s_setprio(0);
    BAR();
    // ---- phase 1 ----
#pragma unroll
    for (int mt = 0; mt < 4; ++mt) {
      af1[mt][0] = ldsA(buf, arow + 64 + mt * 16, 0);
      af1[mt][1] = ldsA(buf, arow + 64 + mt * 16, 1);
    }
    if (tt + 1 < kT) stB(buf ^ 1, 1, kn1);
    BAR(); LGKM0();
    __builtin_amdgcn_s_setprio(1);
#pragma unroll
    for (int mt = 0; mt < 4; ++mt)
#pragma unroll
      for (int nt = 0; nt < 2; ++nt) {
        acc[4 + mt][nt] = MFMA16(af1[mt][0], bf0[nt][0], acc[4 + mt][nt]);
        acc[4 + mt][nt] = MFMA16(af1[mt][1], bf0[nt][1], acc[4 + mt][nt]);
      }
    __builtin_amdgcn_s_setprio(0);
    BAR();
    // ---- phase 2 ----
#pragma unroll
    for (int nt = 0; nt < 2; ++nt) {
      bf1[nt][0] = ldsB(buf, brow + 32 + nt * 16, 0);
      bf1[nt][1] = ldsB(buf, brow + 32 + nt * 16, 1);
    }
    if (tt + 2 < kT) stA(buf, 0, kn2);
    BAR(); LGKM0();
    __builtin_amdgcn_s_setprio(1);
#pragma unroll
    for (int mt = 0; mt < 4; ++mt)
#pragma unroll
      for (int nt = 0; nt < 2; ++nt) {
        acc[mt][2 + nt] = MFMA16(af0[mt][0], bf1[nt][0], acc[mt][2 + nt]);
        acc[mt][2 + nt] = MFMA16(af0[mt][1], bf1[nt][1], acc[mt][2 + nt]);
      }
    __builtin_amdgcn_s_setprio(0);
    BAR();
    // ---- phase 3 ----
    if (tt + 2 < kT) stB(buf, 0, kn2);
    BAR();
    __builtin_amdgcn_s_setprio(1);
#pragma unroll
    for (int mt = 0; mt < 4; ++mt)
#pragma unroll
      for (int nt = 0; nt < 2; ++nt) {
        acc[4 + mt][2 + nt] = MFMA16(af1[mt][0], bf1[nt][0], acc[4 + mt][2 + nt]);
        acc[4 + mt][2 + nt] = MFMA16(af1[mt][1], bf1[nt][1], acc[4 + mt][2 + nt]);
      }
    __builtin_amdgcn_s_setprio(0);
    if (tt + 2 < kT) asm volatile("s_waitcnt vmcnt(4)" ::: "memory");
    else             asm volatile("s_waitcnt vmcnt(0)" ::: "memory");
    BAR();
  }
#undef BAR
#undef LGKM0

#pragma unroll
  for (int mf = 0; mf < 8; ++mf) {
#pragma unroll
    for (int nf = 0; nf < 4; ++nf) {
      const int n = bn * 256 + wni * 64 + nf * 16 + l16;
      const float bb = bias[n];
#pragma unroll
      for (int rr = 0; rr < 4; ++rr) {
        const int m = bm * 256 + wmi * 128 + mf * 16 + quad * 4 + rr;
        float val = acc[mf][nf][rr] + bb;
        if constexpr (EPI == 0) {
          int which = n >> 11, d2 = n & 2047;
          int hh = d2 >> 6, hd = d2 & 63;
          if (which == 0)
            qo[((size_t)hh * Sq + m) * HDm + hd] = __float2bfloat16(val * 0.125f);
          else if (which == 1)
            ko[((size_t)hh * Sq + m) * HDm + hd] = __float2bfloat16(val);
          else
            vo[((size_t)hh * HDm + hd) * Sq + m] = __float2bfloat16(val);
        } else {
          float gg = 0.5f * val * (1.0f + erff(val * 0.70710678118654752f));
          outb[(size_t)m * N + n] = __float2bfloat16(gg);
        }
      }
    }
  }
}

// ---------- 128x128 bf16 MFMA GEMM, 2-buf dist-1, split-K partials ----------
// split-K via blockIdx.z: bz==0 writes f32 addsrc+bias+val; bz>=1 writes bf16
// partials into slot (bz-1). Grid z=4 -> 1024 blocks = 4 blocks/CU co-resident
// (TLP hides the per-step vmcnt(0) drain latency; grid size was the cap).
template <int EPI>
__global__ __launch_bounds__(256)
void gemm_kernel(const __hip_bfloat16* __restrict__ A,
                 const __hip_bfloat16* __restrict__ Bt,
                 int N, int K, int Ksub,
                 const float* __restrict__ bias,
                 const float* __restrict__ addsrc,
                 float* __restrict__ outf,
                 __hip_bfloat16* __restrict__ po) {
  __shared__ __align__(16) __hip_bfloat16 As[2][128 * 32];
  __shared__ __align__(16) __hip_bfloat16 Bs[2][128 * 32];
  const int t = threadIdx.x;
  const int lane = t & 63, w = t >> 6, quad = lane >> 4, l16 = lane & 15;
  const int nbx = gridDim.x;
  const int id = blockIdx.y * nbx + blockIdx.x;
  const int chunk = (nbx * 16) >> 3;
  const int nid = (id & 7) * chunk + (id >> 3);
  const int bn = nid >> 4, bm = nid & 15;
  const int bz = blockIdx.z;
  const int wm = (w & 1) * 64, wn = (w >> 1) * 64;
  const __hip_bfloat16* Abase = A + (size_t)bm * 128 * K;
  const __hip_bfloat16* Bbase = Bt + (size_t)bn * 128 * K;
  const int kBeg = bz * Ksub;
  const int kSteps = Ksub / 32;

  const int c0 = t, c1 = t + 256;
  const int r0 = c0 >> 2, g0 = ((c0 & 3) - (r0 >> 1)) & 3;
  const int r1 = c1 >> 2, g1 = ((c1 & 3) - (r1 >> 1)) & 3;
  const __hip_bfloat16* a0p = Abase + (size_t)r0 * K + g0 * 8;
  const __hip_bfloat16* a1p = Abase + (size_t)r1 * K + g1 * 8;
  const __hip_bfloat16* b0p = Bbase + (size_t)r0 * K + g0 * 8;
  const __hip_bfloat16* b1p = Bbase + (size_t)r1 * K + g1 * 8;

  auto stage = [&](int b, int k0) {
    async_ld16(a0p + k0, &As[b][c0 * 8]);
    async_ld16(a1p + k0, &As[b][c1 * 8]);
    async_ld16(b0p + k0, &Bs[b][c0 * 8]);
    async_ld16(b1p + k0, &Bs[b][c1 * 8]);
  };

  f32x4 acc[4][4] = {};
  auto compute = [&](int b) {
    bf16x8 af[4], bfv[4];
#pragma unroll
    for (int i = 0; i < 4; ++i) {
      int row = wm + i * 16 + l16;
      int p = (quad + (row >> 1)) & 3;
      af[i] = *(const bf16x8*)(&As[b][row * 32 + p * 8]);
    }
#pragma unroll
    for (int i = 0; i < 4; ++i) {
      int row = wn + i * 16 + l16;
      int p = (quad + (row >> 1)) & 3;
      bfv[i] = *(const bf16x8*)(&Bs[b][row * 32 + p * 8]);
    }
#pragma unroll
    for (int mt = 0; mt < 4; ++mt)
#pragma unroll
      for (int nt = 0; nt < 4; ++nt)
        acc[mt][nt] = MFMA16(af[mt], bfv[nt], acc[mt][nt]);
  };

#define PIPE_BAR() asm volatile("s_waitcnt vmcnt(0)\n\ts_barrier" ::: "memory")
  stage(0, kBeg);
  PIPE_BAR();
  int buf = 0;
  for (int i = 0; i < kSteps; ++i) {
    if (i + 1 < kSteps) stage(buf ^ 1, kBeg + (i + 1) * 32);
    compute(buf);
    PIPE_BAR();
    buf ^= 1;
  }
#undef PIPE_BAR

#pragma unroll
  for (int mt = 0; mt < 4; ++mt) {
#pragma unroll
    for (int nt = 0; nt < 4; ++nt) {
      const int n = bn * 128 + wn + nt * 16 + l16;
      const float bz2 = bias[n];
#pragma unroll
      for (int r = 0; r < 4; ++r) {
        const int m = bm * 128 + wm + mt * 16 + quad * 4 + r;
        float val = acc[mt][nt][r];
        if (bz == 0)
          outf[(size_t)m * N + n] = addsrc[(size_t)m * N + n] + bz2 + val;
        else
          po[(size_t)(bz - 1) * Sq * Dm + (size_t)m * N + n] = __float2bfloat16(val);
      }
    }
  }
}

// ---------- flash attention, paired q-tiles (i, 31-i), double-buffered K/V ----
__global__ __launch_bounds__(256)
void attn_kernel(const __hip_bfloat16* __restrict__ qb,
                 const __hip_bfloat16* __restrict__ kb,
                 const __hip_bfloat16* __restrict__ vt,
                 const float* __restrict__ alibi,
                 __hip_bfloat16* __restrict__ ctx) {
  __shared__ __align__(16) __hip_bfloat16 Kl[2][64 * 64];
  __shared__ __align__(16) __hip_bfloat16 Vl[2][64 * 64];   // [d][key]
  __shared__ __align__(16) __hip_bfloat16 Pl[4][16 * 64];   // per-wave P tile
  const int pi = blockIdx.x, h = blockIdx.y;
  const int qA = pi, qB = (Sq / 64 - 1) - pi;
  const int t = threadIdx.x, w = t >> 6, lane = t & 63, quad = lane >> 4, l16 = lane & 15;
  const __hip_bfloat16* qh = qb + (size_t)h * Sq * HDm;
  const __hip_bfloat16* kh = kb + (size_t)h * Sq * HDm;
  const __hip_bfloat16* vh = vt + (size_t)h * HDm * Sq;
  const float* al = alibi + (size_t)h * Sq;

  const int rA = qA * 64 + w * 16 + l16;
  const int rB = qB * 64 + w * 16 + l16;
  const bf16x8 qA0 = *(const bf16x8*)(qh + (size_t)rA * HDm + quad * 8);
  const bf16x8 qA1 = *(const bf16x8*)(qh + (size_t)rA * HDm + 32 + quad * 8);
  const bf16x8 qB0 = *(const bf16x8*)(qh + (size_t)rB * HDm + quad * 8);
  const bf16x8 qB1 = *(const bf16x8*)(qh + (size_t)rB * HDm + 32 + quad * 8);

  auto stageS = [&](int b, int s) {
    const int kbk = (s <= qA) ? s : s - qA - 1;
#pragma unroll
    for (int j = 0; j < 2; ++j) {
      int c = j * 256 + t;
      int row = c >> 3;
      int swz = (c & 7) ^ (row & 7);
      async_ld16(kh + (size_t)(kbk * 64 + row) * HDm + swz * 8, &Kl[b][c * 8]);
      async_ld16(vh + (size_t)row * Sq + kbk * 64 + swz * 8, &Vl[b][c * 8]);
    }
  };

  f32x4 o[4] = {};
  float m_i[4], l_i[4];
#pragma unroll
  for (int r = 0; r < 4; ++r) { m_i[r] = -3e38f; l_i[r] = 0.f; }

  const int total = qA + qB + 2;  // 33
  stageS(0, 0);
  int buf = 0;
  for (int s = 0; s < total; ++s, buf ^= 1) {
    __syncthreads();
    if (s + 1 < total) stageS(buf ^ 1, s + 1);
    const bool ph = (s > qA);
    const int kbk = ph ? s - qA - 1 : s;
    const int qblk = ph ? qB : qA;
    const bf16x8 a0 = ph ? qB0 : qA0;
    const bf16x8 a1 = ph ? qB1 : qA1;

    f32x4 sf[4];
    const f32x4 zero = {};
#pragma unroll
    for (int nt = 0; nt < 4; ++nt) {
      int row = nt * 16 + l16;
      bf16x8 kf0 = *(const bf16x8*)(&Kl[buf][row * 64 + ((quad ^ (row & 7)) << 3)]);
      bf16x8 kf1 = *(const bf16x8*)(&Kl[buf][row * 64 + (((4 + quad) ^ (row & 7)) << 3)]);
      sf[nt] = __builtin_amdgcn_mfma_f32_16x16x32_bf16(a0, kf0, zero, 0, 0, 0);
      sf[nt] = __builtin_amdgcn_mfma_f32_16x16x32_bf16(a1, kf1, sf[nt], 0, 0, 0);
    }
    const bool diag = (kbk == qblk);
    float mrow[4] = {-3e38f, -3e38f, -3e38f, -3e38f};
#pragma unroll
    for (int nt = 0; nt < 4; ++nt) {
      const float ab = al[kbk * 64 + nt * 16 + l16] * 0.125f;
      const int kcol = nt * 16 + l16;
#pragma unroll
      for (int r = 0; r < 4; ++r) {
        float vv = sf[nt][r] + ab;
        if (diag && kcol > w * 16 + quad * 4 + r) vv = -3e38f;
        sf[nt][r] = vv;
        mrow[r] = fmaxf(mrow[r], vv);
      }
    }
#pragma unroll
    for (int off = 8; off > 0; off >>= 1)
#pragma unroll
      for (int r = 0; r < 4; ++r)
        mrow[r] = fmaxf(mrow[r], __shfl_xor(mrow[r], off, 64));
    float alpha[4], rs[4], p[4][4];
#pragma unroll
    for (int r = 0; r < 4; ++r) {
      float mn = fmaxf(m_i[r], mrow[r]);
      alpha[r] = __expf(m_i[r] - mn);
      m_i[r] = mn;
    }
#pragma unroll
    for (int nt = 0; nt < 4; ++nt)
#pragma unroll
      for (int r = 0; r < 4; ++r) p[nt][r] = __expf(sf[nt][r] - m_i[r]);
#pragma unroll
    for (int r = 0; r < 4; ++r) rs[r] = p[0][r] + p[1][r] + p[2][r] + p[3][r];
#pragma unroll
    for (int off = 8; off > 0; off >>= 1)
#pragma unroll
      for (int r = 0; r < 4; ++r) rs[r] += __shfl_xor(rs[r], off, 64);
#pragma unroll
    for (int r = 0; r < 4; ++r) l_i[r] = l_i[r] * alpha[r] + rs[r];
#pragma unroll
    for (int dt = 0; dt < 4; ++dt)
#pragma unroll
      for (int r = 0; r < 4; ++r) o[dt][r] *= alpha[r];
    __hip_bfloat16* pw = &Pl[w][0];
#pragma unroll
    for (int nt = 0; nt < 4; ++nt)
#pragma unroll
      for (int r = 0; r < 4; ++r) {
        int prow = quad * 4 + r;
        int e = nt * 16 + l16;
        int c16 = e >> 3;
        pw[prow * 64 + ((c16 ^ (prow & 7)) << 3) + (e & 7)] = __float2bfloat16(p[nt][r]);
      }
    asm volatile("s_waitcnt lgkmcnt(0)" ::: "memory");
    const bf16x8 pa0 = *(const bf16x8*)(pw + l16 * 64 + ((quad ^ (l16 & 7)) << 3));
    const bf16x8 pa1 = *(const bf16x8*)(pw + l16 * 64 + (((4 + quad) ^ (l16 & 7)) << 3));
#pragma unroll
    for (int dt = 0; dt < 4; ++dt) {
      int row = dt * 16 + l16;
      bf16x8 v0 = *(const bf16x8*)(&Vl[buf][row * 64 + ((quad ^ (row & 7)) << 3)]);
      bf16x8 v1 = *(const bf16x8*)(&Vl[buf][row * 64 + (((4 + quad) ^ (row & 7)) << 3)]);
      o[dt] = __builtin_amdgcn_mfma_f32_16x16x32_bf16(pa0, v0, o[dt], 0, 0, 0);
      o[dt] = __builtin_amdgcn_mfma_f32_16x16x32_bf16(pa1, v1, o[dt], 0, 0, 0);
    }
    if (s == qA) {
#pragma unroll
      for (int dt = 0; dt < 4; ++dt)
#pragma unroll
        for (int r = 0; r < 4; ++r) {
          int srow = qA * 64 + w * 16 + quad * 4 + r;
          ctx[(size_t)srow * Dm + h * HDm + dt * 16 + l16] =
              __float2bfloat16(o[dt][r] / l_i[r]);
          o[dt][r] = 0.f;
        }
#pragma unroll
      for (int r = 0; r < 4; ++r) { m_i[r] = -3e38f; l_i[r] = 0.f; }
    }
  }
#pragma unroll
  for (int dt = 0; dt < 4; ++dt)
#pragma unroll
    for (int r = 0; r < 4; ++r) {
      int srow = qB * 64 + w * 16 + quad * 4 + r;
      ctx[(size_t)srow * Dm + h * HDm + dt * 16 + l16] =
          __float2bfloat16(o[dt][r] / l_i[r]);
    }
}

extern "C" void kernel_launch(void* const* d_in, const int* in_sizes, int n_in,
                              void* d_out, int out_size, void* d_ws, size_t ws_size,
                              hipStream_t stream) {
  const float* x     = (const float*)d_in[0];
  const float* alibi = (const float*)d_in[1];
  const float* ln1g  = (const float*)d_in[3];
  const float* ln1b  = (const float*)d_in[4];
  const float* ln2g  = (const float*)d_in[5];
  const float* ln2b  = (const float*)d_in[6];
  const float* wqkv  = (const float*)d_in[7];
  const float* bqkv  = (const float*)d_in[8];
  const float* wo    = (const float*)d_in[9];
  const float* bo    = (const float*)d_in[10];
  const float* w1    = (const float*)d_in[11];
  const float* b1    = (const float*)d_in[12];
  const float* w2    = (const float*)d_in[13];
  const float* b2    = (const float*)d_in[14];
  float* out = (float*)d_out;

  char* p = (char*)d_ws;
  auto alloc = [&](size_t bytes) {
    char* r = p;
    p += (bytes + 255) & ~(size_t)255;
    return r;
  };
  constexpr size_t SD2 = (size_t)Sq * Dm * 2;
  char* R2 = alloc((size_t)FFm * Dm * 2);
  char* R1 = alloc(4 * SD2);
  __hip_bfloat16* hb    = (__hip_bfloat16*)alloc(SD2);
  float*          resb  = (float*)alloc((size_t)Sq * Dm * 4);
  __hip_bfloat16* part3 = (__hip_bfloat16*)alloc(3 * SD2);

  __hip_bfloat16* wqkvT = (__hip_bfloat16*)R2;
  __hip_bfloat16* w1T   = (__hip_bfloat16*)R2;
  __hip_bfloat16* w2T   = (__hip_bfloat16*)R2;
  __hip_bfloat16* qbuf  = (__hip_bfloat16*)(R1 + 0 * SD2);
  __hip_bfloat16* kbuf  = (__hip_bfloat16*)(R1 + 1 * SD2);
  __hip_bfloat16* vtbuf = (__hip_bfloat16*)(R1 + 2 * SD2);
  __hip_bfloat16* ctxb  = (__hip_bfloat16*)(R1 + 3 * SD2);
  __hip_bfloat16* woT   = (__hip_bfloat16*)(R1 + 0 * SD2);  // after attn
  __hip_bfloat16* t1b   = (__hip_bfloat16*)R1;              // after proj

  // 1) wqkv transpose+cast, ln1
  tcast_kernel<<<dim3(3 * Dm / 64, Dm / 64), 256, 0, stream>>>(wqkv, wqkvT, Dm, 3 * Dm);
  ln_kernel<<<Sq, 256, 0, stream>>>(x, ln1g, ln1b, hb);
  // 2) QKV gemm (256-tile)
  gemm256_kernel<0><<<dim3((3 * Dm / 256) * (Sq / 256)), 512, 0, stream>>>(
      hb, wqkvT, 3 * Dm, Dm, bqkv, nullptr, qbuf, kbuf, vtbuf);
  // 3) w1 transpose
  tcast_kernel<<<dim3(FFm / 64, Dm / 64), 256, 0, stream>>>(w1, w1T, Dm, FFm);
  // 4) flash attention
  attn_kernel<<<dim3(Sq / 128, NH), 256, 0, stream>>>(qbuf, kbuf, vtbuf, alibi, ctxb);
  // 5) wo transpose
  tcast_kernel<<<dim3(Dm / 64, Dm / 64), 256, 0, stream>>>(wo, woT, Dm, Dm);
  // 6) attn proj + residual -> resb (fp32), split-K=4 (1024 blocks = 4/CU)
  gemm_kernel<3><<<dim3(Dm / 128, Sq / 128, 4), 256, 0, stream>>>(
      ctxb, woT, Dm, Dm, Dm / 4, bo, x, resb, part3);
  // 7) fused 3-partial add + ln2
  lnfuse_kernel<<<Sq, 256, 0, stream>>>(resb, part3, ln2g, ln2b, hb);
  // 8) mlp up + gelu (256-tile) -> t1b
  gemm256_kernel<2><<<dim3((FFm / 256) * (Sq / 256)), 512, 0, stream>>>(
      hb, w1T, FFm, Dm, b1, t1b, nullptr, nullptr, nullptr);
  // 9) w2 transpose
  tcast_kernel<<<dim3(Dm / 64, FFm / 64), 256, 0, stream>>>(w2, w2T, FFm, Dm);
  // 10) mlp down, split-K=4 (1024 blocks = 4/CU)
  gemm_kernel<3><<<dim3(Dm / 128, Sq / 128, 4), 256, 0, stream>>>(
      t1b, w2T, Dm, FFm, FFm / 4, b2, resb, out, part3);
  // 11) out += partials
  addp3_kernel<<<(Sq * Dm) / 1024, 256, 0, stream>>>(out, part3);
}

// Round 7
// 649.587 us; speedup vs baseline: 1.1253x; 1.1253x over previous
//
#include <hip/hip_runtime.h>
#include <hip/hip_bf16.h>
#include <cstdint>
#include <cstddef>

static constexpr int Sq  = 2048;
static constexpr int Dm  = 2048;
static constexpr int NH  = 32;
static constexpr int HDm = 64;
static constexpr int FFm = 8192;

typedef __bf16 bf16x8 __attribute__((ext_vector_type(8)));
typedef float  f32x4  __attribute__((ext_vector_type(4)));
typedef unsigned short ushort4v __attribute__((ext_vector_type(4)));

__device__ __forceinline__ void async_ld16(const void* g, void* l) {
  __builtin_amdgcn_global_load_lds((const __attribute__((address_space(1))) void*)g,
                                   (__attribute__((address_space(3))) void*)l, 16, 0, 0);
}

#define MFMA16(a, b, c) __builtin_amdgcn_mfma_f32_16x16x32_bf16(a, b, c, 0, 0, 0)

// ---------- transpose + cast: in[K][N] f32 -> out[N][K] bf16, vectorized ----
__global__ __launch_bounds__(256)
void tcast_kernel(const float* __restrict__ in, __hip_bfloat16* __restrict__ out,
                  int K, int N) {
  __shared__ float tile[64][65];
  const int tc = blockIdx.x * 64;
  const int tr = blockIdx.y * 64;
  const int t = threadIdx.x;
  const int f16 = t & 15;
  const int rg  = t >> 4;
#pragma unroll
  for (int k = 0; k < 4; ++k) {
    const int r = rg + 16 * k;
    const float4 v = *(const float4*)(in + (size_t)(tr + r) * N + tc + f16 * 4);
    tile[r][f16 * 4 + 0] = v.x;
    tile[r][f16 * 4 + 1] = v.y;
    tile[r][f16 * 4 + 2] = v.z;
    tile[r][f16 * 4 + 3] = v.w;
  }
  __syncthreads();
#pragma unroll
  for (int k = 0; k < 4; ++k) {
    const int cc = rg + 16 * k;
    ushort4v o;
#pragma unroll
    for (int j = 0; j < 4; ++j) {
      union { __hip_bfloat16 h; unsigned short u; } cv;
      cv.h = __float2bfloat16(tile[f16 * 4 + j][cc]);
      o[j] = cv.u;
    }
    *(ushort4v*)(out + (size_t)(tc + cc) * K + tr + f16 * 4) = o;
  }
}

// ---------- layernorm row kernel: x f32 -> out bf16 ----------
__global__ __launch_bounds__(256)
void ln_kernel(const float* __restrict__ x, const float* __restrict__ g,
               const float* __restrict__ b, __hip_bfloat16* __restrict__ out) {
  __shared__ float red[4];
  const int t = threadIdx.x;
  const float* xr = x + (size_t)blockIdx.x * Dm;
  float v[8];
  float s = 0.f;
#pragma unroll
  for (int i = 0; i < 8; ++i) { v[i] = xr[t + i * 256]; s += v[i]; }
#pragma unroll
  for (int off = 32; off > 0; off >>= 1) s += __shfl_down(s, off, 64);
  if ((t & 63) == 0) red[t >> 6] = s;
  __syncthreads();
  const float mean = (red[0] + red[1] + red[2] + red[3]) * (1.f / Dm);
  __syncthreads();
  float vs = 0.f;
#pragma unroll
  for (int i = 0; i < 8; ++i) { float d = v[i] - mean; vs += d * d; }
#pragma unroll
  for (int off = 32; off > 0; off >>= 1) vs += __shfl_down(vs, off, 64);
  if ((t & 63) == 0) red[t >> 6] = vs;
  __syncthreads();
  const float inv = rsqrtf((red[0] + red[1] + red[2] + red[3]) * (1.f / Dm) + 1e-5f);
  __hip_bfloat16* orow = out + (size_t)blockIdx.x * Dm;
#pragma unroll
  for (int i = 0; i < 8; ++i) {
    int c = t + i * 256;
    orow[c] = __float2bfloat16((v[i] - mean) * inv * g[c] + b[c]);
  }
}

// ---------- fused: resb += part (bf16); layernorm(resb) -> out bf16 ----------
__global__ __launch_bounds__(256)
void lnfuse_kernel(float* __restrict__ resb, const __hip_bfloat16* __restrict__ part,
                   const float* __restrict__ g, const float* __restrict__ b,
                   __hip_bfloat16* __restrict__ out) {
  __shared__ float red[4];
  const int t = threadIdx.x;
  float* xr = resb + (size_t)blockIdx.x * Dm;
  const __hip_bfloat16* pr = part + (size_t)blockIdx.x * Dm;
  float v[8];
  float s = 0.f;
#pragma unroll
  for (int i = 0; i < 8; ++i) {
    int c = t + i * 256;
    v[i] = xr[c] + (float)pr[c];
    xr[c] = v[i];
    s += v[i];
  }
#pragma unroll
  for (int off = 32; off > 0; off >>= 1) s += __shfl_down(s, off, 64);
  if ((t & 63) == 0) red[t >> 6] = s;
  __syncthreads();
  const float mean = (red[0] + red[1] + red[2] + red[3]) * (1.f / Dm);
  __syncthreads();
  float vs = 0.f;
#pragma unroll
  for (int i = 0; i < 8; ++i) { float d = v[i] - mean; vs += d * d; }
#pragma unroll
  for (int off = 32; off > 0; off >>= 1) vs += __shfl_down(vs, off, 64);
  if ((t & 63) == 0) red[t >> 6] = vs;
  __syncthreads();
  const float inv = rsqrtf((red[0] + red[1] + red[2] + red[3]) * (1.f / Dm) + 1e-5f);
  __hip_bfloat16* orow = out + (size_t)blockIdx.x * Dm;
#pragma unroll
  for (int i = 0; i < 8; ++i) {
    int c = t + i * 256;
    orow[c] = __float2bfloat16((v[i] - mean) * inv * g[c] + b[c]);
  }
}

// ---------- 256x256 4-phase bf16 MFMA GEMM (best-measured config) ----------
template <int EPI>
__global__ __launch_bounds__(512)
void gemm256_kernel(const __hip_bfloat16* __restrict__ A,
                    const __hip_bfloat16* __restrict__ Bt,
                    int N, int K,
                    const float* __restrict__ bias,
                    __hip_bfloat16* __restrict__ outb,
                    __hip_bfloat16* __restrict__ qo,
                    __hip_bfloat16* __restrict__ ko,
                    __hip_bfloat16* __restrict__ vo) {
  __shared__ __align__(16) __hip_bfloat16 As[2][256 * 64];
  __shared__ __align__(16) __hip_bfloat16 Bs[2][256 * 64];
  const int t = threadIdx.x;
  const int lane = t & 63, w = t >> 6, quad = lane >> 4, l16 = lane & 15;
  const int wmi = w >> 2, wni = w & 3;
  const int nwg = gridDim.x;
  const int id = blockIdx.x;
  const int xcd = id & 7, q = nwg >> 3, r_ = nwg & 7;
  const int swz = (xcd < r_ ? xcd * (q + 1) : r_ * (q + 1) + (xcd - r_) * q) + (id >> 3);
  const int bm = swz & 7, bn = swz >> 3;
  const __hip_bfloat16* Abase = A + (size_t)bm * 256 * K;
  const __hip_bfloat16* Bbase = Bt + (size_t)bn * 256 * K;
  const int kT = K / 64;

  const int c0 = t, c1 = t + 512;
  const int r0 = c0 >> 3, k0c = (c0 & 7) ^ (r0 & 7);
  const int r1 = c1 >> 3, k1c = (c1 & 7) ^ (r1 & 7);
  const size_t o0 = (size_t)r0 * K + k0c * 8;
  const size_t o1 = (size_t)r1 * K + k1c * 8;
  const size_t halfO = (size_t)128 * K;

  auto stA = [&](int b, int h, int k0) {
    async_ld16(Abase + h * halfO + o0 + k0, &As[b][h * 8192 + c0 * 8]);
    async_ld16(Abase + h * halfO + o1 + k0, &As[b][h * 8192 + c1 * 8]);
  };
  auto stB = [&](int b, int h, int k0) {
    async_ld16(Bbase + h * halfO + o0 + k0, &Bs[b][h * 8192 + c0 * 8]);
    async_ld16(Bbase + h * halfO + o1 + k0, &Bs[b][h * 8192 + c1 * 8]);
  };
  auto ldsA = [&](int b, int r, int ks) {
    return *(const bf16x8*)(&As[b][r * 64 + (((ks * 4 + quad) ^ (r & 7)) << 3)]);
  };
  auto ldsB = [&](int b, int r, int ks) {
    return *(const bf16x8*)(&Bs[b][r * 64 + (((ks * 4 + quad) ^ (r & 7)) << 3)]);
  };

  f32x4 acc[8][4] = {};
  bf16x8 af0[4][2], af1[4][2], bf0[2][2], bf1[2][2];
  const int arow = wmi * 128 + l16;
  const int brow = wni * 64 + l16;

#define BAR() asm volatile("s_barrier" ::: "memory")
#define LGKM0() do { asm volatile("s_waitcnt lgkmcnt(0)" ::: "memory"); \
                     __builtin_amdgcn_sched_barrier(0); } while (0)

  stA(0, 0, 0); stA(0, 1, 0); stB(0, 0, 0); stB(0, 1, 0);
  stA(1, 0, 64); stB(1, 0, 64);
  asm volatile("s_waitcnt vmcnt(4)" ::: "memory");
  BAR();

  for (int tt = 0; tt < kT; ++tt) {
    const int buf = tt & 1;
    const int kn1 = (tt + 1) * 64, kn2 = (tt + 2) * 64;
    // ---- phase 0 ----
#pragma unroll
    for (int mt = 0; mt < 4; ++mt) {
      af0[mt][0] = ldsA(buf, arow + mt * 16, 0);
      af0[mt][1] = ldsA(buf, arow + mt * 16, 1);
    }
#pragma unroll
    for (int nt = 0; nt < 2; ++nt) {
      bf0[nt][0] = ldsB(buf, brow + nt * 16, 0);
      bf0[nt][1] = ldsB(buf, brow + nt * 16, 1);
    }
    if (tt + 1 < kT) stA(buf ^ 1, 1, kn1);
    BAR(); LGKM0();
    __builtin_amdgcn_s_setprio(1);
#pragma unroll
    for (int mt = 0; mt < 4; ++mt)
#pragma unroll
      for (int nt = 0; nt < 2; ++nt) {
        acc[mt][nt] = MFMA16(af0[mt][0], bf0[nt][0], acc[mt][nt]);
        acc[mt][nt] = MFMA16(af0[mt][1], bf0[nt][1], acc[mt][nt]);
      }
    __builtin_amdgcn_s_setprio(0);
    BAR();
    // ---- phase 1 ----
#pragma unroll
    for (int mt = 0; mt < 4; ++mt) {
      af1[mt][0] = ldsA(buf, arow + 64 + mt * 16, 0);
      af1[mt][1] = ldsA(buf, arow + 64 + mt * 16, 1);
    }
    if (tt + 1 < kT) stB(buf ^ 1, 1, kn1);
    BAR(); LGKM0();
    __builtin_amdgcn_s_setprio(1);
#pragma unroll
    for (int mt = 0; mt < 4; ++mt)
#pragma unroll
      for (int nt = 0; nt < 2; ++nt) {
        acc[4 + mt][nt] = MFMA16(af1[mt][0], bf0[nt][0], acc[4 + mt][nt]);
        acc[4 + mt][nt] = MFMA16(af1[mt][1], bf0[nt][1], acc[4 + mt][nt]);
      }
    __builtin_amdgcn_s_setprio(0);
    BAR();
    // ---- phase 2 ----
#pragma unroll
    for (int nt = 0; nt < 2; ++nt) {
      bf1[nt][0] = ldsB(buf, brow + 32 + nt * 16, 0);
      bf1[nt][1] = ldsB(buf, brow + 32 + nt * 16, 1);
    }
    if (tt + 2 < kT) stA(buf, 0, kn2);
    BAR(); LGKM0();
    __builtin_amdgcn_s_setprio(1);
#pragma unroll
    for (int mt = 0; mt < 4; ++mt)
#pragma unroll
      for (int nt = 0; nt < 2; ++nt) {
        acc[mt][2 + nt] = MFMA16(af0[mt][0], bf1[nt][0], acc[mt][2 + nt]);
        acc[mt][2 + nt] = MFMA16(af0[mt][1], bf1[nt][1], acc[mt][2 + nt]);
      }
    __builtin_amdgcn_s_setprio(0);
    BAR();
    // ---- phase 3 ----
    if (tt + 2 < kT) stB(buf, 0, kn2);
    BAR();
    __builtin_amdgcn_s_setprio(1);
#pragma unroll
    for (int mt = 0; mt < 4; ++mt)
#pragma unroll
      for (int nt = 0; nt < 2; ++nt) {
        acc[4 + mt][2 + nt] = MFMA16(af1[mt][0], bf1[nt][0], acc[4 + mt][2 + nt]);
        acc[4 + mt][2 + nt] = MFMA16(af1[mt][1], bf1[nt][1], acc[4 + mt][2 + nt]);
      }
    __builtin_amdgcn_s_setprio(0);
    if (tt + 2 < kT) asm volatile("s_waitcnt vmcnt(4)" ::: "memory");
    else             asm volatile("s_waitcnt vmcnt(0)" ::: "memory");
    BAR();
  }
#undef BAR
#undef LGKM0

#pragma unroll
  for (int mf = 0; mf < 8; ++mf) {
#pragma unroll
    for (int nf = 0; nf < 4; ++nf) {
      const int n = bn * 256 + wni * 64 + nf * 16 + l16;
      const float bb = bias[n];
#pragma unroll
      for (int rr = 0; rr < 4; ++rr) {
        const int m = bm * 256 + wmi * 128 + mf * 16 + quad * 4 + rr;
        float val = acc[mf][nf][rr] + bb;
        if constexpr (EPI == 0) {
          int which = n >> 11, d2 = n & 2047;
          int hh = d2 >> 6, hd = d2 & 63;
          if (which == 0)
            qo[((size_t)hh * Sq + m) * HDm + hd] = __float2bfloat16(val * 0.125f);
          else if (which == 1)
            ko[((size_t)hh * Sq + m) * HDm + hd] = __float2bfloat16(val);
          else
            vo[((size_t)hh * HDm + hd) * Sq + m] = __float2bfloat16(val);
        } else {
          float gg = 0.5f * val * (1.0f + erff(val * 0.70710678118654752f));
          outb[(size_t)m * N + n] = __float2bfloat16(gg);
        }
      }
    }
  }
}

// ---------- 128x128 bf16 MFMA GEMM, 2-buf dist-1 (best-measured config) ------
template <int EPI>
__global__ __launch_bounds__(256)
void gemm_kernel(const __hip_bfloat16* __restrict__ A,
                 const __hip_bfloat16* __restrict__ Bt,
                 int N, int K, int Ksub,
                 const float* __restrict__ bias,
                 const float* __restrict__ addsrc,
                 float* __restrict__ outf,
                 __hip_bfloat16* __restrict__ po) {
  __shared__ __align__(16) __hip_bfloat16 As[2][128 * 32];
  __shared__ __align__(16) __hip_bfloat16 Bs[2][128 * 32];
  const int t = threadIdx.x;
  const int lane = t & 63, w = t >> 6, quad = lane >> 4, l16 = lane & 15;
  const int nbx = gridDim.x;
  const int id = blockIdx.y * nbx + blockIdx.x;
  const int chunk = (nbx * 16) >> 3;
  const int nid = (id & 7) * chunk + (id >> 3);
  const int bn = nid >> 4, bm = nid & 15;
  const int bz = blockIdx.z;
  const int wm = (w & 1) * 64, wn = (w >> 1) * 64;
  const __hip_bfloat16* Abase = A + (size_t)bm * 128 * K;
  const __hip_bfloat16* Bbase = Bt + (size_t)bn * 128 * K;
  const int kBeg = bz * Ksub;
  const int kSteps = Ksub / 32;

  const int c0 = t, c1 = t + 256;
  const int r0 = c0 >> 2, g0 = ((c0 & 3) - (r0 >> 1)) & 3;
  const int r1 = c1 >> 2, g1 = ((c1 & 3) - (r1 >> 1)) & 3;
  const __hip_bfloat16* a0p = Abase + (size_t)r0 * K + g0 * 8;
  const __hip_bfloat16* a1p = Abase + (size_t)r1 * K + g1 * 8;
  const __hip_bfloat16* b0p = Bbase + (size_t)r0 * K + g0 * 8;
  const __hip_bfloat16* b1p = Bbase + (size_t)r1 * K + g1 * 8;

  auto stage = [&](int b, int k0) {
    async_ld16(a0p + k0, &As[b][c0 * 8]);
    async_ld16(a1p + k0, &As[b][c1 * 8]);
    async_ld16(b0p + k0, &Bs[b][c0 * 8]);
    async_ld16(b1p + k0, &Bs[b][c1 * 8]);
  };

  f32x4 acc[4][4] = {};
  auto compute = [&](int b) {
    bf16x8 af[4], bfv[4];
#pragma unroll
    for (int i = 0; i < 4; ++i) {
      int row = wm + i * 16 + l16;
      int p = (quad + (row >> 1)) & 3;
      af[i] = *(const bf16x8*)(&As[b][row * 32 + p * 8]);
    }
#pragma unroll
    for (int i = 0; i < 4; ++i) {
      int row = wn + i * 16 + l16;
      int p = (quad + (row >> 1)) & 3;
      bfv[i] = *(const bf16x8*)(&Bs[b][row * 32 + p * 8]);
    }
#pragma unroll
    for (int mt = 0; mt < 4; ++mt)
#pragma unroll
      for (int nt = 0; nt < 4; ++nt)
        acc[mt][nt] = MFMA16(af[mt], bfv[nt], acc[mt][nt]);
  };

#define PIPE_BAR() asm volatile("s_waitcnt vmcnt(0)\n\ts_barrier" ::: "memory")
  stage(0, kBeg);
  PIPE_BAR();
  int buf = 0;
  for (int i = 0; i < kSteps; ++i) {
    if (i + 1 < kSteps) stage(buf ^ 1, kBeg + (i + 1) * 32);
    compute(buf);
    PIPE_BAR();
    buf ^= 1;
  }
#undef PIPE_BAR

#pragma unroll
  for (int mt = 0; mt < 4; ++mt) {
#pragma unroll
    for (int nt = 0; nt < 4; ++nt) {
      const int n = bn * 128 + wn + nt * 16 + l16;
      const float bz2 = bias[n];
#pragma unroll
      for (int r = 0; r < 4; ++r) {
        const int m = bm * 128 + wm + mt * 16 + quad * 4 + r;
        float val = acc[mt][nt][r];
        if (bz == 0)
          outf[(size_t)m * N + n] = addsrc[(size_t)m * N + n] + bz2 + val;
        else
          po[(size_t)m * N + n] = __float2bfloat16(val);
      }
    }
  }
}

// ---------- out[i] += (float)p[i], vectorized x4 ----------
__global__ __launch_bounds__(256)
void addp_kernel(float* __restrict__ out, const __hip_bfloat16* __restrict__ p) {
  const int i = (blockIdx.x * 256 + threadIdx.x) * 4;
  float4 o = *(const float4*)(out + i);
  const __hip_bfloat16* pp = p + i;
  o.x += (float)pp[0]; o.y += (float)pp[1]; o.z += (float)pp[2]; o.w += (float)pp[3];
  *(float4*)(out + i) = o;
}

// ---------- flash attention, paired q-tiles (i, 31-i), double-buffered K/V ----
__global__ __launch_bounds__(256)
void attn_kernel(const __hip_bfloat16* __restrict__ qb,
                 const __hip_bfloat16* __restrict__ kb,
                 const __hip_bfloat16* __restrict__ vt,
                 const float* __restrict__ alibi,
                 __hip_bfloat16* __restrict__ ctx) {
  __shared__ __align__(16) __hip_bfloat16 Kl[2][64 * 64];
  __shared__ __align__(16) __hip_bfloat16 Vl[2][64 * 64];   // [d][key]
  __shared__ __align__(16) __hip_bfloat16 Pl[4][16 * 64];   // per-wave P tile
  const int pi = blockIdx.x, h = blockIdx.y;
  const int qA = pi, qB = (Sq / 64 - 1) - pi;
  const int t = threadIdx.x, w = t >> 6, lane = t & 63, quad = lane >> 4, l16 = lane & 15;
  const __hip_bfloat16* qh = qb + (size_t)h * Sq * HDm;
  const __hip_bfloat16* kh = kb + (size_t)h * Sq * HDm;
  const __hip_bfloat16* vh = vt + (size_t)h * HDm * Sq;
  const float* al = alibi + (size_t)h * Sq;

  const int rA = qA * 64 + w * 16 + l16;
  const int rB = qB * 64 + w * 16 + l16;
  const bf16x8 qA0 = *(const bf16x8*)(qh + (size_t)rA * HDm + quad * 8);
  const bf16x8 qA1 = *(const bf16x8*)(qh + (size_t)rA * HDm + 32 + quad * 8);
  const bf16x8 qB0 = *(const bf16x8*)(qh + (size_t)rB * HDm + quad * 8);
  const bf16x8 qB1 = *(const bf16x8*)(qh + (size_t)rB * HDm + 32 + quad * 8);

  auto stageS = [&](int b, int s) {
    const int kbk = (s <= qA) ? s : s - qA - 1;
#pragma unroll
    for (int j = 0; j < 2; ++j) {
      int c = j * 256 + t;
      int row = c >> 3;
      int swz = (c & 7) ^ (row & 7);
      async_ld16(kh + (size_t)(kbk * 64 + row) * HDm + swz * 8, &Kl[b][c * 8]);
      async_ld16(vh + (size_t)row * Sq + kbk * 64 + swz * 8, &Vl[b][c * 8]);
    }
  };

  f32x4 o[4] = {};
  float m_i[4], l_i[4];
#pragma unroll
  for (int r = 0; r < 4; ++r) { m_i[r] = -3e38f; l_i[r] = 0.f; }

  const int total = qA + qB + 2;  // 33
  stageS(0, 0);
  int buf = 0;
  for (int s = 0; s < total; ++s, buf ^= 1) {
    __syncthreads();
    if (s + 1 < total) stageS(buf ^ 1, s + 1);
    const bool ph = (s > qA);
    const int kbk = ph ? s - qA - 1 : s;
    const int qblk = ph ? qB : qA;
    const bf16x8 a0 = ph ? qB0 : qA0;
    const bf16x8 a1 = ph ? qB1 : qA1;

    f32x4 sf[4];
    const f32x4 zero = {};
#pragma unroll
    for (int nt = 0; nt < 4; ++nt) {
      int row = nt * 16 + l16;
      bf16x8 kf0 = *(const bf16x8*)(&Kl[buf][row * 64 + ((quad ^ (row & 7)) << 3)]);
      bf16x8 kf1 = *(const bf16x8*)(&Kl[buf][row * 64 + (((4 + quad) ^ (row & 7)) << 3)]);
      sf[nt] = __builtin_amdgcn_mfma_f32_16x16x32_bf16(a0, kf0, zero, 0, 0, 0);
      sf[nt] = __builtin_amdgcn_mfma_f32_16x16x32_bf16(a1, kf1, sf[nt], 0, 0, 0);
    }
    const bool diag = (kbk == qblk);
    float mrow[4] = {-3e38f, -3e38f, -3e38f, -3e38f};
#pragma unroll
    for (int nt = 0; nt < 4; ++nt) {
      const float ab = al[kbk * 64 + nt * 16 + l16] * 0.125f;
      const int kcol = nt * 16 + l16;
#pragma unroll
      for (int r = 0; r < 4; ++r) {
        float vv = sf[nt][r] + ab;
        if (diag && kcol > w * 16 + quad * 4 + r) vv = -3e38f;
        sf[nt][r] = vv;
        mrow[r] = fmaxf(mrow[r], vv);
      }
    }
#pragma unroll
    for (int off = 8; off > 0; off >>= 1)
#pragma unroll
      for (int r = 0; r < 4; ++r)
        mrow[r] = fmaxf(mrow[r], __shfl_xor(mrow[r], off, 64));
    float alpha[4], rs[4], p[4][4];
#pragma unroll
    for (int r = 0; r < 4; ++r) {
      float mn = fmaxf(m_i[r], mrow[r]);
      alpha[r] = __expf(m_i[r] - mn);
      m_i[r] = mn;
    }
#pragma unroll
    for (int nt = 0; nt < 4; ++nt)
#pragma unroll
      for (int r = 0; r < 4; ++r) p[nt][r] = __expf(sf[nt][r] - m_i[r]);
#pragma unroll
    for (int r = 0; r < 4; ++r) rs[r] = p[0][r] + p[1][r] + p[2][r] + p[3][r];
#pragma unroll
    for (int off = 8; off > 0; off >>= 1)
#pragma unroll
      for (int r = 0; r < 4; ++r) rs[r] += __shfl_xor(rs[r], off, 64);
#pragma unroll
    for (int r = 0; r < 4; ++r) l_i[r] = l_i[r] * alpha[r] + rs[r];
#pragma unroll
    for (int dt = 0; dt < 4; ++dt)
#pragma unroll
      for (int r = 0; r < 4; ++r) o[dt][r] *= alpha[r];
    __hip_bfloat16* pw = &Pl[w][0];
#pragma unroll
    for (int nt = 0; nt < 4; ++nt)
#pragma unroll
      for (int r = 0; r < 4; ++r) {
        int prow = quad * 4 + r;
        int e = nt * 16 + l16;
        int c16 = e >> 3;
        pw[prow * 64 + ((c16 ^ (prow & 7)) << 3) + (e & 7)] = __float2bfloat16(p[nt][r]);
      }
    asm volatile("s_waitcnt lgkmcnt(0)" ::: "memory");
    const bf16x8 pa0 = *(const bf16x8*)(pw + l16 * 64 + ((quad ^ (l16 & 7)) << 3));
    const bf16x8 pa1 = *(const bf16x8*)(pw + l16 * 64 + (((4 + quad) ^ (l16 & 7)) << 3));
#pragma unroll
    for (int dt = 0; dt < 4; ++dt) {
      int row = dt * 16 + l16;
      bf16x8 v0 = *(const bf16x8*)(&Vl[buf][row * 64 + ((quad ^ (row & 7)) << 3)]);
      bf16x8 v1 = *(const bf16x8*)(&Vl[buf][row * 64 + (((4 + quad) ^ (row & 7)) << 3)]);
      o[dt] = __builtin_amdgcn_mfma_f32_16x16x32_bf16(pa0, v0, o[dt], 0, 0, 0);
      o[dt] = __builtin_amdgcn_mfma_f32_16x16x32_bf16(pa1, v1, o[dt], 0, 0, 0);
    }
    if (s == qA) {
#pragma unroll
      for (int dt = 0; dt < 4; ++dt)
#pragma unroll
        for (int r = 0; r < 4; ++r) {
          int srow = qA * 64 + w * 16 + quad * 4 + r;
          ctx[(size_t)srow * Dm + h * HDm + dt * 16 + l16] =
              __float2bfloat16(o[dt][r] / l_i[r]);
          o[dt][r] = 0.f;
        }
#pragma unroll
      for (int r = 0; r < 4; ++r) { m_i[r] = -3e38f; l_i[r] = 0.f; }
    }
  }
#pragma unroll
  for (int dt = 0; dt < 4; ++dt)
#pragma unroll
    for (int r = 0; r < 4; ++r) {
      int srow = qB * 64 + w * 16 + quad * 4 + r;
      ctx[(size_t)srow * Dm + h * HDm + dt * 16 + l16] =
          __float2bfloat16(o[dt][r] / l_i[r]);
    }
}

extern "C" void kernel_launch(void* const* d_in, const int* in_sizes, int n_in,
                              void* d_out, int out_size, void* d_ws, size_t ws_size,
                              hipStream_t stream) {
  const float* x     = (const float*)d_in[0];
  const float* alibi = (const float*)d_in[1];
  const float* ln1g  = (const float*)d_in[3];
  const float* ln1b  = (const float*)d_in[4];
  const float* ln2g  = (const float*)d_in[5];
  const float* ln2b  = (const float*)d_in[6];
  const float* wqkv  = (const float*)d_in[7];
  const float* bqkv  = (const float*)d_in[8];
  const float* wo    = (const float*)d_in[9];
  const float* bo    = (const float*)d_in[10];
  const float* w1    = (const float*)d_in[11];
  const float* b1    = (const float*)d_in[12];
  const float* w2    = (const float*)d_in[13];
  const float* b2    = (const float*)d_in[14];
  float* out = (float*)d_out;

  char* p = (char*)d_ws;
  auto alloc = [&](size_t bytes) {
    char* r = p;
    p += (bytes + 255) & ~(size_t)255;
    return r;
  };
  constexpr size_t SD2 = (size_t)Sq * Dm * 2;
  char* R2 = alloc((size_t)FFm * Dm * 2);
  char* R1 = alloc(4 * SD2);
  __hip_bfloat16* hb   = (__hip_bfloat16*)alloc(SD2);
  float*          resb = (float*)alloc((size_t)Sq * Dm * 4);

  __hip_bfloat16* wqkvT = (__hip_bfloat16*)R2;
  __hip_bfloat16* w1T   = (__hip_bfloat16*)R2;
  __hip_bfloat16* w2T   = (__hip_bfloat16*)R2;
  __hip_bfloat16* qbuf  = (__hip_bfloat16*)(R1 + 0 * SD2);
  __hip_bfloat16* kbuf  = (__hip_bfloat16*)(R1 + 1 * SD2);
  __hip_bfloat16* vtbuf = (__hip_bfloat16*)(R1 + 2 * SD2);
  __hip_bfloat16* ctxb  = (__hip_bfloat16*)(R1 + 3 * SD2);
  __hip_bfloat16* woT   = (__hip_bfloat16*)(R1 + 0 * SD2);  // after attn
  __hip_bfloat16* t1b   = (__hip_bfloat16*)R1;              // after proj
  __hip_bfloat16* part  = hb;                               // split-K partials

  // 1) wqkv transpose+cast, ln1
  tcast_kernel<<<dim3(3 * Dm / 64, Dm / 64), 256, 0, stream>>>(wqkv, wqkvT, Dm, 3 * Dm);
  ln_kernel<<<Sq, 256, 0, stream>>>(x, ln1g, ln1b, hb);
  // 2) QKV gemm (256-tile)
  gemm256_kernel<0><<<dim3((3 * Dm / 256) * (Sq / 256)), 512, 0, stream>>>(
      hb, wqkvT, 3 * Dm, Dm, bqkv, nullptr, qbuf, kbuf, vtbuf);
  // 3) w1 transpose
  tcast_kernel<<<dim3(FFm / 64, Dm / 64), 256, 0, stream>>>(w1, w1T, Dm, FFm);
  // 4) flash attention
  attn_kernel<<<dim3(Sq / 128, NH), 256, 0, stream>>>(qbuf, kbuf, vtbuf, alibi, ctxb);
  // 5) wo transpose
  tcast_kernel<<<dim3(Dm / 64, Dm / 64), 256, 0, stream>>>(wo, woT, Dm, Dm);
  // 6) attn proj + residual -> resb (fp32), split-K=2
  gemm_kernel<3><<<dim3(Dm / 128, Sq / 128, 2), 256, 0, stream>>>(
      ctxb, woT, Dm, Dm, Dm / 2, bo, x, resb, part);
  // 7) fused addp + ln2
  lnfuse_kernel<<<Sq, 256, 0, stream>>>(resb, part, ln2g, ln2b, hb);
  // 8) mlp up + gelu (256-tile) -> t1b
  gemm256_kernel<2><<<dim3((FFm / 256) * (Sq / 256)), 512, 0, stream>>>(
      hb, w1T, FFm, Dm, b1, t1b, nullptr, nullptr, nullptr);
  // 9) w2 transpose
  tcast_kernel<<<dim3(Dm / 64, FFm / 64), 256, 0, stream>>>(w2, w2T, FFm, Dm);
  // 10) mlp down, split-K=2
  gemm_kernel<3><<<dim3(Dm / 128, Sq / 128, 2), 256, 0, stream>>>(
      t1b, w2T, Dm, FFm, FFm / 2, b2, resb, out, part);
  // 11) out += part
  addp_kernel<<<(Sq * Dm) / 1024, 256, 0, stream>>>(out, part);
}

// Round 8
// 644.164 us; speedup vs baseline: 1.1347x; 1.0084x over previous
//
#include <hip/hip_runtime.h>
#include <hip/hip_bf16.h>
#include <cstdint>
#include <cstddef>

static constexpr int Sq  = 2048;
static constexpr int Dm  = 2048;
static constexpr int NH  = 32;
static constexpr int HDm = 64;
static constexpr int FFm = 8192;

typedef __bf16 bf16x8 __attribute__((ext_vector_type(8)));
typedef float  f32x4  __attribute__((ext_vector_type(4)));
typedef unsigned short ushort4v __attribute__((ext_vector_type(4)));

__device__ __forceinline__ void async_ld16(const void* g, void* l) {
  __builtin_amdgcn_global_load_lds((const __attribute__((address_space(1))) void*)g,
                                   (__attribute__((address_space(3))) void*)l, 16, 0, 0);
}

#define MFMA16(a, b, c) __builtin_amdgcn_mfma_f32_16x16x32_bf16(a, b, c, 0, 0, 0)

// ---------- transpose + cast: in[K][N] f32 -> out[N][K] bf16, vectorized ----
__global__ __launch_bounds__(256)
void tcast_kernel(const float* __restrict__ in, __hip_bfloat16* __restrict__ out,
                  int K, int N) {
  __shared__ float tile[64][65];
  const int tc = blockIdx.x * 64;
  const int tr = blockIdx.y * 64;
  const int t = threadIdx.x;
  const int f16 = t & 15;
  const int rg  = t >> 4;
#pragma unroll
  for (int k = 0; k < 4; ++k) {
    const int r = rg + 16 * k;
    const float4 v = *(const float4*)(in + (size_t)(tr + r) * N + tc + f16 * 4);
    tile[r][f16 * 4 + 0] = v.x;
    tile[r][f16 * 4 + 1] = v.y;
    tile[r][f16 * 4 + 2] = v.z;
    tile[r][f16 * 4 + 3] = v.w;
  }
  __syncthreads();
#pragma unroll
  for (int k = 0; k < 4; ++k) {
    const int cc = rg + 16 * k;
    ushort4v o;
#pragma unroll
    for (int j = 0; j < 4; ++j) {
      union { __hip_bfloat16 h; unsigned short u; } cv;
      cv.h = __float2bfloat16(tile[f16 * 4 + j][cc]);
      o[j] = cv.u;
    }
    *(ushort4v*)(out + (size_t)(tc + cc) * K + tr + f16 * 4) = o;
  }
}

// ---------- layernorm row kernel: x f32 -> out bf16 ----------
__global__ __launch_bounds__(256)
void ln_kernel(const float* __restrict__ x, const float* __restrict__ g,
               const float* __restrict__ b, __hip_bfloat16* __restrict__ out) {
  __shared__ float red[4];
  const int t = threadIdx.x;
  const float* xr = x + (size_t)blockIdx.x * Dm;
  float v[8];
  float s = 0.f;
#pragma unroll
  for (int i = 0; i < 8; ++i) { v[i] = xr[t + i * 256]; s += v[i]; }
#pragma unroll
  for (int off = 32; off > 0; off >>= 1) s += __shfl_down(s, off, 64);
  if ((t & 63) == 0) red[t >> 6] = s;
  __syncthreads();
  const float mean = (red[0] + red[1] + red[2] + red[3]) * (1.f / Dm);
  __syncthreads();
  float vs = 0.f;
#pragma unroll
  for (int i = 0; i < 8; ++i) { float d = v[i] - mean; vs += d * d; }
#pragma unroll
  for (int off = 32; off > 0; off >>= 1) vs += __shfl_down(vs, off, 64);
  if ((t & 63) == 0) red[t >> 6] = vs;
  __syncthreads();
  const float inv = rsqrtf((red[0] + red[1] + red[2] + red[3]) * (1.f / Dm) + 1e-5f);
  __hip_bfloat16* orow = out + (size_t)blockIdx.x * Dm;
#pragma unroll
  for (int i = 0; i < 8; ++i) {
    int c = t + i * 256;
    orow[c] = __float2bfloat16((v[i] - mean) * inv * g[c] + b[c]);
  }
}

// ---------- fused: resb += 3 partial slots; layernorm(resb) -> out bf16 ------
__global__ __launch_bounds__(256)
void lnfuse_kernel(float* __restrict__ resb, const __hip_bfloat16* __restrict__ part,
                   const float* __restrict__ g, const float* __restrict__ b,
                   __hip_bfloat16* __restrict__ out) {
  __shared__ float red[4];
  const int t = threadIdx.x;
  const size_t st = (size_t)Sq * Dm;
  float* xr = resb + (size_t)blockIdx.x * Dm;
  const __hip_bfloat16* p0 = part + (size_t)blockIdx.x * Dm;
  float v[8];
  float s = 0.f;
#pragma unroll
  for (int i = 0; i < 8; ++i) {
    int c = t + i * 256;
    v[i] = xr[c] + (float)p0[c] + (float)p0[st + c] + (float)p0[2 * st + c];
    xr[c] = v[i];
    s += v[i];
  }
#pragma unroll
  for (int off = 32; off > 0; off >>= 1) s += __shfl_down(s, off, 64);
  if ((t & 63) == 0) red[t >> 6] = s;
  __syncthreads();
  const float mean = (red[0] + red[1] + red[2] + red[3]) * (1.f / Dm);
  __syncthreads();
  float vs = 0.f;
#pragma unroll
  for (int i = 0; i < 8; ++i) { float d = v[i] - mean; vs += d * d; }
#pragma unroll
  for (int off = 32; off > 0; off >>= 1) vs += __shfl_down(vs, off, 64);
  if ((t & 63) == 0) red[t >> 6] = vs;
  __syncthreads();
  const float inv = rsqrtf((red[0] + red[1] + red[2] + red[3]) * (1.f / Dm) + 1e-5f);
  __hip_bfloat16* orow = out + (size_t)blockIdx.x * Dm;
#pragma unroll
  for (int i = 0; i < 8; ++i) {
    int c = t + i * 256;
    orow[c] = __float2bfloat16((v[i] - mean) * inv * g[c] + b[c]);
  }
}

// ---------- out[i] += sum of 3 bf16 partial slots, vectorized x4 ----------
__global__ __launch_bounds__(256)
void addp3_kernel(float* __restrict__ out, const __hip_bfloat16* __restrict__ p) {
  const size_t i = ((size_t)blockIdx.x * 256 + threadIdx.x) * 4;
  const size_t st = (size_t)Sq * Dm;
  float4 o = *(const float4*)(out + i);
#pragma unroll
  for (int s = 0; s < 3; ++s) {
    const __hip_bfloat16* pp = p + s * st + i;
    o.x += (float)pp[0]; o.y += (float)pp[1]; o.z += (float)pp[2]; o.w += (float)pp[3];
  }
  *(float4*)(out + i) = o;
}

// ---------- 256x256 4-phase bf16 MFMA GEMM (best-measured config) ----------
template <int EPI>
__global__ __launch_bounds__(512)
void gemm256_kernel(const __hip_bfloat16* __restrict__ A,
                    const __hip_bfloat16* __restrict__ Bt,
                    int N, int K,
                    const float* __restrict__ bias,
                    __hip_bfloat16* __restrict__ outb,
                    __hip_bfloat16* __restrict__ qo,
                    __hip_bfloat16* __restrict__ ko,
                    __hip_bfloat16* __restrict__ vo) {
  __shared__ __align__(16) __hip_bfloat16 As[2][256 * 64];
  __shared__ __align__(16) __hip_bfloat16 Bs[2][256 * 64];
  const int t = threadIdx.x;
  const int lane = t & 63, w = t >> 6, quad = lane >> 4, l16 = lane & 15;
  const int wmi = w >> 2, wni = w & 3;
  const int nwg = gridDim.x;
  const int id = blockIdx.x;
  const int xcd = id & 7, q = nwg >> 3, r_ = nwg & 7;
  const int swz = (xcd < r_ ? xcd * (q + 1) : r_ * (q + 1) + (xcd - r_) * q) + (id >> 3);
  const int bm = swz & 7, bn = swz >> 3;
  const __hip_bfloat16* Abase = A + (size_t)bm * 256 * K;
  const __hip_bfloat16* Bbase = Bt + (size_t)bn * 256 * K;
  const int kT = K / 64;

  const int c0 = t, c1 = t + 512;
  const int r0 = c0 >> 3, k0c = (c0 & 7) ^ (r0 & 7);
  const int r1 = c1 >> 3, k1c = (c1 & 7) ^ (r1 & 7);
  const size_t o0 = (size_t)r0 * K + k0c * 8;
  const size_t o1 = (size_t)r1 * K + k1c * 8;
  const size_t halfO = (size_t)128 * K;

  auto stA = [&](int b, int h, int k0) {
    async_ld16(Abase + h * halfO + o0 + k0, &As[b][h * 8192 + c0 * 8]);
    async_ld16(Abase + h * halfO + o1 + k0, &As[b][h * 8192 + c1 * 8]);
  };
  auto stB = [&](int b, int h, int k0) {
    async_ld16(Bbase + h * halfO + o0 + k0, &Bs[b][h * 8192 + c0 * 8]);
    async_ld16(Bbase + h * halfO + o1 + k0, &Bs[b][h * 8192 + c1 * 8]);
  };
  auto ldsA = [&](int b, int r, int ks) {
    return *(const bf16x8*)(&As[b][r * 64 + (((ks * 4 + quad) ^ (r & 7)) << 3)]);
  };
  auto ldsB = [&](int b, int r, int ks) {
    return *(const bf16x8*)(&Bs[b][r * 64 + (((ks * 4 + quad) ^ (r & 7)) << 3)]);
  };

  f32x4 acc[8][4] = {};
  bf16x8 af0[4][2], af1[4][2], bf0[2][2], bf1[2][2];
  const int arow = wmi * 128 + l16;
  const int brow = wni * 64 + l16;

#define BAR() asm volatile("s_barrier" ::: "memory")
#define LGKM0() do { asm volatile("s_waitcnt lgkmcnt(0)" ::: "memory"); \
                     __builtin_amdgcn_sched_barrier(0); } while (0)

  stA(0, 0, 0); stA(0, 1, 0); stB(0, 0, 0); stB(0, 1, 0);
  stA(1, 0, 64); stB(1, 0, 64);
  asm volatile("s_waitcnt vmcnt(4)" ::: "memory");
  BAR();

  for (int tt = 0; tt < kT; ++tt) {
    const int buf = tt & 1;
    const int kn1 = (tt + 1) * 64, kn2 = (tt + 2) * 64;
    // ---- phase 0 ----
#pragma unroll
    for (int mt = 0; mt < 4; ++mt) {
      af0[mt][0] = ldsA(buf, arow + mt * 16, 0);
      af0[mt][1] = ldsA(buf, arow + mt * 16, 1);
    }
#pragma unroll
    for (int nt = 0; nt < 2; ++nt) {
      bf0[nt][0] = ldsB(buf, brow + nt * 16, 0);
      bf0[nt][1] = ldsB(buf, brow + nt * 16, 1);
    }
    if (tt + 1 < kT) stA(buf ^ 1, 1, kn1);
    BAR(); LGKM0();
    __builtin_amdgcn_s_setprio(1);
#pragma unroll
    for (int mt = 0; mt < 4; ++mt)
#pragma unroll
      for (int nt = 0; nt < 2; ++nt) {
        acc[mt][nt] = MFMA16(af0[mt][0], bf0[nt][0], acc[mt][nt]);
        acc[mt][nt] = MFMA16(af0[mt][1], bf0[nt][1], acc[mt][nt]);
      }
    __builtin_amdgcn_s_setprio(0);
    BAR();
    // ---- phase 1 ----
#pragma unroll
    for (int mt = 0; mt < 4; ++mt) {
      af1[mt][0] = ldsA(buf, arow + 64 + mt * 16, 0);
      af1[mt][1] = ldsA(buf, arow + 64 + mt * 16, 1);
    }
    if (tt + 1 < kT) stB(buf ^ 1, 1, kn1);
    BAR(); LGKM0();
    __builtin_amdgcn_s_setprio(1);
#pragma unroll
    for (int mt = 0; mt < 4; ++mt)
#pragma unroll
      for (int nt = 0; nt < 2; ++nt) {
        acc[4 + mt][nt] = MFMA16(af1[mt][0], bf0[nt][0], acc[4 + mt][nt]);
        acc[4 + mt][nt] = MFMA16(af1[mt][1], bf0[nt][1], acc[4 + mt][nt]);
      }
    __builtin_amdgcn_s_setprio(0);
    BAR();
    // ---- phase 2 ----
#pragma unroll
    for (int nt = 0; nt < 2; ++nt) {
      bf1[nt][0] = ldsB(buf, brow + 32 + nt * 16, 0);
      bf1[nt][1] = ldsB(buf, brow + 32 + nt * 16, 1);
    }
    if (tt + 2 < kT) stA(buf, 0, kn2);
    BAR(); LGKM0();
    __builtin_amdgcn_s_setprio(1);
#pragma unroll
    for (int mt = 0; mt < 4; ++mt)
#pragma unroll
      for (int nt = 0; nt < 2; ++nt) {
        acc[mt][2 + nt] = MFMA16(af0[mt][0], bf1[nt][0], acc[mt][2 + nt]);
        acc[mt][2 + nt] = MFMA16(af0[mt][1], bf1[nt][1], acc[mt][2 + nt]);
      }
    __builtin_amdgcn_s_setprio(0);
    BAR();
    // ---- phase 3 ----
    if (tt + 2 < kT) stB(buf, 0, kn2);
    BAR();
    __builtin_amdgcn_s_setprio(1);
#pragma unroll
    for (int mt = 0; mt < 4; ++mt)
#pragma unroll
      for (int nt = 0; nt < 2; ++nt) {
        acc[4 + mt][2 + nt] = MFMA16(af1[mt][0], bf1[nt][0], acc[4 + mt][2 + nt]);
        acc[4 + mt][2 + nt] = MFMA16(af1[mt][1], bf1[nt][1], acc[4 + mt][2 + nt]);
      }
    __builtin_amdgcn_s_setprio(0);
    if (tt + 2 < kT) asm volatile("s_waitcnt vmcnt(4)" ::: "memory");
    else             asm volatile("s_waitcnt vmcnt(0)" ::: "memory");
    BAR();
  }
#undef BAR
#undef LGKM0

#pragma unroll
  for (int mf = 0; mf < 8; ++mf) {
#pragma unroll
    for (int nf = 0; nf < 4; ++nf) {
      const int n = bn * 256 + wni * 64 + nf * 16 + l16;
      const float bb = bias[n];
#pragma unroll
      for (int rr = 0; rr < 4; ++rr) {
        const int m = bm * 256 + wmi * 128 + mf * 16 + quad * 4 + rr;
        float val = acc[mf][nf][rr] + bb;
        if constexpr (EPI == 0) {
          int which = n >> 11, d2 = n & 2047;
          int hh = d2 >> 6, hd = d2 & 63;
          if (which == 0)
            qo[((size_t)hh * Sq + m) * HDm + hd] = __float2bfloat16(val * 0.125f);
          else if (which == 1)
            ko[((size_t)hh * Sq + m) * HDm + hd] = __float2bfloat16(val);
          else
            vo[((size_t)hh * HDm + hd) * Sq + m] = __float2bfloat16(val);
        } else {
          float gg = 0.5f * val * (1.0f + erff(val * 0.70710678118654752f));
          outb[(size_t)m * N + n] = __float2bfloat16(gg);
        }
      }
    }
  }
}

// ---------- 128x128 bf16 MFMA GEMM, 2-buf dist-1, split-K partials ----------
// split-K via blockIdx.z: bz==0 writes f32 addsrc+bias+val; bz>=1 writes bf16
// partials into slot (bz-1). Grid z=4 -> 1024 blocks = 4 blocks/CU co-resident
// (m102 occupancy curve: 1/CU=320TF, 2/CU~611TF, 4/CU~833TF for this
// structure; grid size, not LDS/VGPR, was the cap at 2/CU).
template <int EPI>
__global__ __launch_bounds__(256)
void gemm_kernel(const __hip_bfloat16* __restrict__ A,
                 const __hip_bfloat16* __restrict__ Bt,
                 int N, int K, int Ksub,
                 const float* __restrict__ bias,
                 const float* __restrict__ addsrc,
                 float* __restrict__ outf,
                 __hip_bfloat16* __restrict__ po) {
  __shared__ __align__(16) __hip_bfloat16 As[2][128 * 32];
  __shared__ __align__(16) __hip_bfloat16 Bs[2][128 * 32];
  const int t = threadIdx.x;
  const int lane = t & 63, w = t >> 6, quad = lane >> 4, l16 = lane & 15;
  const int nbx = gridDim.x;
  const int id = blockIdx.y * nbx + blockIdx.x;
  const int chunk = (nbx * 16) >> 3;
  const int nid = (id & 7) * chunk + (id >> 3);
  const int bn = nid >> 4, bm = nid & 15;
  const int bz = blockIdx.z;
  const int wm = (w & 1) * 64, wn = (w >> 1) * 64;
  const __hip_bfloat16* Abase = A + (size_t)bm * 128 * K;
  const __hip_bfloat16* Bbase = Bt + (size_t)bn * 128 * K;
  const int kBeg = bz * Ksub;
  const int kSteps = Ksub / 32;

  const int c0 = t, c1 = t + 256;
  const int r0 = c0 >> 2, g0 = ((c0 & 3) - (r0 >> 1)) & 3;
  const int r1 = c1 >> 2, g1 = ((c1 & 3) - (r1 >> 1)) & 3;
  const __hip_bfloat16* a0p = Abase + (size_t)r0 * K + g0 * 8;
  const __hip_bfloat16* a1p = Abase + (size_t)r1 * K + g1 * 8;
  const __hip_bfloat16* b0p = Bbase + (size_t)r0 * K + g0 * 8;
  const __hip_bfloat16* b1p = Bbase + (size_t)r1 * K + g1 * 8;

  auto stage = [&](int b, int k0) {
    async_ld16(a0p + k0, &As[b][c0 * 8]);
    async_ld16(a1p + k0, &As[b][c1 * 8]);
    async_ld16(b0p + k0, &Bs[b][c0 * 8]);
    async_ld16(b1p + k0, &Bs[b][c1 * 8]);
  };

  f32x4 acc[4][4] = {};
  auto compute = [&](int b) {
    bf16x8 af[4], bfv[4];
#pragma unroll
    for (int i = 0; i < 4; ++i) {
      int row = wm + i * 16 + l16;
      int p = (quad + (row >> 1)) & 3;
      af[i] = *(const bf16x8*)(&As[b][row * 32 + p * 8]);
    }
#pragma unroll
    for (int i = 0; i < 4; ++i) {
      int row = wn + i * 16 + l16;
      int p = (quad + (row >> 1)) & 3;
      bfv[i] = *(const bf16x8*)(&Bs[b][row * 32 + p * 8]);
    }
#pragma unroll
    for (int mt = 0; mt < 4; ++mt)
#pragma unroll
      for (int nt = 0; nt < 4; ++nt)
        acc[mt][nt] = MFMA16(af[mt], bfv[nt], acc[mt][nt]);
  };

#define PIPE_BAR() asm volatile("s_waitcnt vmcnt(0)\n\ts_barrier" ::: "memory")
  stage(0, kBeg);
  PIPE_BAR();
  int buf = 0;
  for (int i = 0; i < kSteps; ++i) {
    if (i + 1 < kSteps) stage(buf ^ 1, kBeg + (i + 1) * 32);
    compute(buf);
    PIPE_BAR();
    buf ^= 1;
  }
#undef PIPE_BAR

#pragma unroll
  for (int mt = 0; mt < 4; ++mt) {
#pragma unroll
    for (int nt = 0; nt < 4; ++nt) {
      const int n = bn * 128 + wn + nt * 16 + l16;
      const float bz2 = bias[n];
#pragma unroll
      for (int r = 0; r < 4; ++r) {
        const int m = bm * 128 + wm + mt * 16 + quad * 4 + r;
        float val = acc[mt][nt][r];
        if (bz == 0)
          outf[(size_t)m * N + n] = addsrc[(size_t)m * N + n] + bz2 + val;
        else
          po[(size_t)(bz - 1) * Sq * Dm + (size_t)m * N + n] = __float2bfloat16(val);
      }
    }
  }
}

// ---------- flash attention, paired q-tiles (i, 31-i), double-buffered K/V ----
__global__ __launch_bounds__(256)
void attn_kernel(const __hip_bfloat16* __restrict__ qb,
                 const __hip_bfloat16* __restrict__ kb,
                 const __hip_bfloat16* __restrict__ vt,
                 const float* __restrict__ alibi,
                 __hip_bfloat16* __restrict__ ctx) {
  __shared__ __align__(16) __hip_bfloat16 Kl[2][64 * 64];
  __shared__ __align__(16) __hip_bfloat16 Vl[2][64 * 64];   // [d][key]
  __shared__ __align__(16) __hip_bfloat16 Pl[4][16 * 64];   // per-wave P tile
  const int pi = blockIdx.x, h = blockIdx.y;
  const int qA = pi, qB = (Sq / 64 - 1) - pi;
  const int t = threadIdx.x, w = t >> 6, lane = t & 63, quad = lane >> 4, l16 = lane & 15;
  const __hip_bfloat16* qh = qb + (size_t)h * Sq * HDm;
  const __hip_bfloat16* kh = kb + (size_t)h * Sq * HDm;
  const __hip_bfloat16* vh = vt + (size_t)h * HDm * Sq;
  const float* al = alibi + (size_t)h * Sq;

  const int rA = qA * 64 + w * 16 + l16;
  const int rB = qB * 64 + w * 16 + l16;
  const bf16x8 qA0 = *(const bf16x8*)(qh + (size_t)rA * HDm + quad * 8);
  const bf16x8 qA1 = *(const bf16x8*)(qh + (size_t)rA * HDm + 32 + quad * 8);
  const bf16x8 qB0 = *(const bf16x8*)(qh + (size_t)rB * HDm + quad * 8);
  const bf16x8 qB1 = *(const bf16x8*)(qh + (size_t)rB * HDm + 32 + quad * 8);

  auto stageS = [&](int b, int s) {
    const int kbk = (s <= qA) ? s : s - qA - 1;
#pragma unroll
    for (int j = 0; j < 2; ++j) {
      int c = j * 256 + t;
      int row = c >> 3;
      int swz = (c & 7) ^ (row & 7);
      async_ld16(kh + (size_t)(kbk * 64 + row) * HDm + swz * 8, &Kl[b][c * 8]);
      async_ld16(vh + (size_t)row * Sq + kbk * 64 + swz * 8, &Vl[b][c * 8]);
    }
  };

  f32x4 o[4] = {};
  float m_i[4], l_i[4];
#pragma unroll
  for (int r = 0; r < 4; ++r) { m_i[r] = -3e38f; l_i[r] = 0.f; }

  const int total = qA + qB + 2;  // 33
  stageS(0, 0);
  int buf = 0;
  for (int s = 0; s < total; ++s, buf ^= 1) {
    __syncthreads();
    if (s + 1 < total) stageS(buf ^ 1, s + 1);
    const bool ph = (s > qA);
    const int kbk = ph ? s - qA - 1 : s;
    const int qblk = ph ? qB : qA;
    const bf16x8 a0 = ph ? qB0 : qA0;
    const bf16x8 a1 = ph ? qB1 : qA1;

    f32x4 sf[4];
    const f32x4 zero = {};
#pragma unroll
    for (int nt = 0; nt < 4; ++nt) {
      int row = nt * 16 + l16;
      bf16x8 kf0 = *(const bf16x8*)(&Kl[buf][row * 64 + ((quad ^ (row & 7)) << 3)]);
      bf16x8 kf1 = *(const bf16x8*)(&Kl[buf][row * 64 + (((4 + quad) ^ (row & 7)) << 3)]);
      sf[nt] = __builtin_amdgcn_mfma_f32_16x16x32_bf16(a0, kf0, zero, 0, 0, 0);
      sf[nt] = __builtin_amdgcn_mfma_f32_16x16x32_bf16(a1, kf1, sf[nt], 0, 0, 0);
    }
    const bool diag = (kbk == qblk);
    float mrow[4] = {-3e38f, -3e38f, -3e38f, -3e38f};
#pragma unroll
    for (int nt = 0; nt < 4; ++nt) {
      const float ab = al[kbk * 64 + nt * 16 + l16] * 0.125f;
      const int kcol = nt * 16 + l16;
#pragma unroll
      for (int r = 0; r < 4; ++r) {
        float vv = sf[nt][r] + ab;
        if (diag && kcol > w * 16 + quad * 4 + r) vv = -3e38f;
        sf[nt][r] = vv;
        mrow[r] = fmaxf(mrow[r], vv);
      }
    }
#pragma unroll
    for (int off = 8; off > 0; off >>= 1)
#pragma unroll
      for (int r = 0; r < 4; ++r)
        mrow[r] = fmaxf(mrow[r], __shfl_xor(mrow[r], off, 64));
    float alpha[4], rs[4], p[4][4];
#pragma unroll
    for (int r = 0; r < 4; ++r) {
      float mn = fmaxf(m_i[r], mrow[r]);
      alpha[r] = __expf(m_i[r] - mn);
      m_i[r] = mn;
    }
#pragma unroll
    for (int nt = 0; nt < 4; ++nt)
#pragma unroll
      for (int r = 0; r < 4; ++r) p[nt][r] = __expf(sf[nt][r] - m_i[r]);
#pragma unroll
    for (int r = 0; r < 4; ++r) rs[r] = p[0][r] + p[1][r] + p[2][r] + p[3][r];
#pragma unroll
    for (int off = 8; off > 0; off >>= 1)
#pragma unroll
      for (int r = 0; r < 4; ++r) rs[r] += __shfl_xor(rs[r], off, 64);
#pragma unroll
    for (int r = 0; r < 4; ++r) l_i[r] = l_i[r] * alpha[r] + rs[r];
#pragma unroll
    for (int dt = 0; dt < 4; ++dt)
#pragma unroll
      for (int r = 0; r < 4; ++r) o[dt][r] *= alpha[r];
    __hip_bfloat16* pw = &Pl[w][0];
#pragma unroll
    for (int nt = 0; nt < 4; ++nt)
#pragma unroll
      for (int r = 0; r < 4; ++r) {
        int prow = quad * 4 + r;
        int e = nt * 16 + l16;
        int c16 = e >> 3;
        pw[prow * 64 + ((c16 ^ (prow & 7)) << 3) + (e & 7)] = __float2bfloat16(p[nt][r]);
      }
    asm volatile("s_waitcnt lgkmcnt(0)" ::: "memory");
    const bf16x8 pa0 = *(const bf16x8*)(pw + l16 * 64 + ((quad ^ (l16 & 7)) << 3));
    const bf16x8 pa1 = *(const bf16x8*)(pw + l16 * 64 + (((4 + quad) ^ (l16 & 7)) << 3));
#pragma unroll
    for (int dt = 0; dt < 4; ++dt) {
      int row = dt * 16 + l16;
      bf16x8 v0 = *(const bf16x8*)(&Vl[buf][row * 64 + ((quad ^ (row & 7)) << 3)]);
      bf16x8 v1 = *(const bf16x8*)(&Vl[buf][row * 64 + (((4 + quad) ^ (row & 7)) << 3)]);
      o[dt] = __builtin_amdgcn_mfma_f32_16x16x32_bf16(pa0, v0, o[dt], 0, 0, 0);
      o[dt] = __builtin_amdgcn_mfma_f32_16x16x32_bf16(pa1, v1, o[dt], 0, 0, 0);
    }
    if (s == qA) {
#pragma unroll
      for (int dt = 0; dt < 4; ++dt)
#pragma unroll
        for (int r = 0; r < 4; ++r) {
          int srow = qA * 64 + w * 16 + quad * 4 + r;
          ctx[(size_t)srow * Dm + h * HDm + dt * 16 + l16] =
              __float2bfloat16(o[dt][r] / l_i[r]);
          o[dt][r] = 0.f;
        }
#pragma unroll
      for (int r = 0; r < 4; ++r) { m_i[r] = -3e38f; l_i[r] = 0.f; }
    }
  }
#pragma unroll
  for (int dt = 0; dt < 4; ++dt)
#pragma unroll
    for (int r = 0; r < 4; ++r) {
      int srow = qB * 64 + w * 16 + quad * 4 + r;
      ctx[(size_t)srow * Dm + h * HDm + dt * 16 + l16] =
          __float2bfloat16(o[dt][r] / l_i[r]);
    }
}

extern "C" void kernel_launch(void* const* d_in, const int* in_sizes, int n_in,
                              void* d_out, int out_size, void* d_ws, size_t ws_size,
                              hipStream_t stream) {
  const float* x     = (const float*)d_in[0];
  const float* alibi = (const float*)d_in[1];
  const float* ln1g  = (const float*)d_in[3];
  const float* ln1b  = (const float*)d_in[4];
  const float* ln2g  = (const float*)d_in[5];
  const float* ln2b  = (const float*)d_in[6];
  const float* wqkv  = (const float*)d_in[7];
  const float* bqkv  = (const float*)d_in[8];
  const float* wo    = (const float*)d_in[9];
  const float* bo    = (const float*)d_in[10];
  const float* w1    = (const float*)d_in[11];
  const float* b1    = (const float*)d_in[12];
  const float* w2    = (const float*)d_in[13];
  const float* b2    = (const float*)d_in[14];
  float* out = (float*)d_out;

  char* p = (char*)d_ws;
  auto alloc = [&](size_t bytes) {
    char* r = p;
    p += (bytes + 255) & ~(size_t)255;
    return r;
  };
  constexpr size_t SD2 = (size_t)Sq * Dm * 2;
  char* R2 = alloc((size_t)FFm * Dm * 2);
  char* R1 = alloc(4 * SD2);
  __hip_bfloat16* hb    = (__hip_bfloat16*)alloc(SD2);
  float*          resb  = (float*)alloc((size_t)Sq * Dm * 4);
  __hip_bfloat16* part3 = (__hip_bfloat16*)alloc(3 * SD2);

  __hip_bfloat16* wqkvT = (__hip_bfloat16*)R2;
  __hip_bfloat16* w1T   = (__hip_bfloat16*)R2;
  __hip_bfloat16* w2T   = (__hip_bfloat16*)R2;
  __hip_bfloat16* qbuf  = (__hip_bfloat16*)(R1 + 0 * SD2);
  __hip_bfloat16* kbuf  = (__hip_bfloat16*)(R1 + 1 * SD2);
  __hip_bfloat16* vtbuf = (__hip_bfloat16*)(R1 + 2 * SD2);
  __hip_bfloat16* ctxb  = (__hip_bfloat16*)(R1 + 3 * SD2);
  __hip_bfloat16* woT   = (__hip_bfloat16*)(R1 + 0 * SD2);  // after attn
  __hip_bfloat16* t1b   = (__hip_bfloat16*)R1;              // after proj

  // 1) wqkv transpose+cast, ln1
  tcast_kernel<<<dim3(3 * Dm / 64, Dm / 64), 256, 0, stream>>>(wqkv, wqkvT, Dm, 3 * Dm);
  ln_kernel<<<Sq, 256, 0, stream>>>(x, ln1g, ln1b, hb);
  // 2) QKV gemm (256-tile)
  gemm256_kernel<0><<<dim3((3 * Dm / 256) * (Sq / 256)), 512, 0, stream>>>(
      hb, wqkvT, 3 * Dm, Dm, bqkv, nullptr, qbuf, kbuf, vtbuf);
  // 3) w1 transpose
  tcast_kernel<<<dim3(FFm / 64, Dm / 64), 256, 0, stream>>>(w1, w1T, Dm, FFm);
  // 4) flash attention
  attn_kernel<<<dim3(Sq / 128, NH), 256, 0, stream>>>(qbuf, kbuf, vtbuf, alibi, ctxb);
  // 5) wo transpose
  tcast_kernel<<<dim3(Dm / 64, Dm / 64), 256, 0, stream>>>(wo, woT, Dm, Dm);
  // 6) attn proj + residual -> resb (fp32), split-K=4 (1024 blocks = 4/CU)
  gemm_kernel<3><<<dim3(Dm / 128, Sq / 128, 4), 256, 0, stream>>>(
      ctxb, woT, Dm, Dm, Dm / 4, bo, x, resb, part3);
  // 7) fused 3-partial add + ln2
  lnfuse_kernel<<<Sq, 256, 0, stream>>>(resb, part3, ln2g, ln2b, hb);
  // 8) mlp up + gelu (256-tile) -> t1b
  gemm256_kernel<2><<<dim3((FFm / 256) * (Sq / 256)), 512, 0, stream>>>(
      hb, w1T, FFm, Dm, b1, t1b, nullptr, nullptr, nullptr);
  // 9) w2 transpose
  tcast_kernel<<<dim3(Dm / 64, FFm / 64), 256, 0, stream>>>(w2, w2T, FFm, Dm);
  // 10) mlp down, split-K=4 (1024 blocks = 4/CU)
  gemm_kernel<3><<<dim3(Dm / 128, Sq / 128, 4), 256, 0, stream>>>(
      t1b, w2T, Dm, FFm, FFm / 4, b2, resb, out, part3);
  // 11) out += partials
  addp3_kernel<<<(Sq * Dm) / 1024, 256, 0, stream>>>(out, part3);
}